// Round 4
// baseline (30.257 us; speedup 1.0000x reference)
//
#include <hip/hip_runtime.h>
#include <hip/hip_bf16.h>
#include <math.h>

namespace {

typedef __bf16 bf16x8 __attribute__((ext_vector_type(8)));
typedef float f32x4 __attribute__((ext_vector_type(4)));

constexpr int L = 64;
constexpr int DH = 64;

// Swizzle key: distinct across BOTH stride-1 and stride-4 row sequences.
__device__ __forceinline__ int kkey(int r) { return (r ^ (r >> 2)) & 7; }

// V^T tile: 64 rows (d) x 64 cols (j), bf16, 128B rows, at lds+0.
__device__ __forceinline__ int swzV(int d, int j) {
  return d * 128 + ((((j >> 3) ^ kkey(d)) & 7) << 4) + (j & 7) * 2;
}
// Per-wave C tile: 16 rows x 64 cols, bf16, 128B rows.
__device__ __forceinline__ int swzC(int r, int j) {
  return r * 128 + ((((j >> 3) ^ kkey(r)) & 7) << 4) + (j & 7) * 2;
}

__device__ __forceinline__ unsigned short bfbits(float f) {
  __bf16 h = (__bf16)f;
  return __builtin_bit_cast(unsigned short, h);
}
__device__ __forceinline__ __bf16 tobf(float f) { return (__bf16)f; }

__global__ __launch_bounds__(256) void mlstm_mfma(
    const float* __restrict__ q, const float* __restrict__ k,
    const float* __restrict__ v, const float* __restrict__ ig,
    const float* __restrict__ fg, float* __restrict__ out) {

  // 4 waves per chunk; wave w owns output rows [16w, 16w+16).
  __shared__ __align__(16) char lds[8192 + 4 * 2048];  // V^T + 4x C tiles
  __shared__ __align__(16) float ea_sh[64];
  __shared__ __align__(16) float eb_sh[64];
  __shared__ __align__(16) float em_sh[64];

  const int tid = threadIdx.x;
  const int w = tid >> 6;    // wave id = output row-block (cb)
  const int lane = tid & 63;
  const int m = lane & 15;
  const int g = lane >> 4;
  const size_t cbase = (size_t)blockIdx.x * (L * DH);
  const size_t gb = (size_t)blockIdx.x * L;

  // ---- V staging loads: cooperative, coalesced float4 -------------------
  const float4* v4 = (const float4*)(v + cbase);
  float4 vbuf[4];
#pragma unroll
  for (int it = 0; it < 4; ++it) vbuf[it] = v4[it * 256 + tid];

  // ---- gate loads (wave 0 only) ------------------------------------------
  float fgv = 0.f, igv = 0.f;
  if (w == 0) {
    fgv = fg[gb + lane];
    igv = ig[gb + lane];
  }

  // ---- Q fragments (own rows) and K fragments (rb <= w), global->reg ----
  bf16x8 qf[2];
#pragma unroll
  for (int kb = 0; kb < 2; ++kb) {
    const int off = (w * 16 + m) * 64 + kb * 32 + g * 8;
    const float4 q0 = *(const float4*)(q + cbase + off);
    const float4 q1 = *(const float4*)(q + cbase + off + 4);
    qf[kb] = bf16x8{tobf(q0.x), tobf(q0.y), tobf(q0.z), tobf(q0.w),
                    tobf(q1.x), tobf(q1.y), tobf(q1.z), tobf(q1.w)};
  }
  bf16x8 kf[4][2];
#pragma unroll
  for (int rb = 0; rb < 4; ++rb) {
    if (rb <= w) {  // wave-uniform
#pragma unroll
      for (int kb = 0; kb < 2; ++kb) {
        const int off = (rb * 16 + m) * 64 + kb * 32 + g * 8;
        const float4 k0 = *(const float4*)(k + cbase + off);
        const float4 k1 = *(const float4*)(k + cbase + off + 4);
        kf[rb][kb] = bf16x8{tobf(k0.x), tobf(k0.y), tobf(k0.z), tobf(k0.w),
                            tobf(k1.x), tobf(k1.y), tobf(k1.z), tobf(k1.w)};
      }
    }
  }

  // ---- gate scan (wave 0): two 64-lane scans, 3 exps ---------------------
  if (w == 0) {
    const float lf = fminf(fgv, 0.f) - log1pf(__expf(-fabsf(fgv)));
    float cum = lf;
#pragma unroll
    for (int o = 1; o < 64; o <<= 1) {
      const float t = __shfl_up(cum, o, 64);
      if (lane >= o) cum += t;
    }
    const float a = igv - cum;
    float b = a;
#pragma unroll
    for (int o = 1; o < 64; o <<= 1) {
      const float t = __shfl_up(b, o, 64);
      if (lane >= o) b = fmaxf(b, t);
    }
    const float bmax = __shfl(b, 63, 64);
    ea_sh[lane] = 0.125f * __expf(a - bmax);  // fold 1/sqrt(DH)
    eb_sh[lane] = __expf(bmax - b);
    em_sh[lane] = __expf(-(b + cum));
  }

  // ---- V^T scatter (cooperative, kkey-swizzled) ---------------------------
  {
    unsigned short* vt = (unsigned short*)lds;
#pragma unroll
    for (int it = 0; it < 4; ++it) {
      const int idx = it * 256 + tid;  // float4 index in the chunk
      const int j = idx >> 4;          // time index
      const int d0 = (idx & 15) * 4;   // feature
      vt[swzV(d0 + 0, j) >> 1] = bfbits(vbuf[it].x);
      vt[swzV(d0 + 1, j) >> 1] = bfbits(vbuf[it].y);
      vt[swzV(d0 + 2, j) >> 1] = bfbits(vbuf[it].z);
      vt[swzV(d0 + 3, j) >> 1] = bfbits(vbuf[it].w);
    }
  }

  __syncthreads();

  // ---- V^T fragments (wave w needs j < 16(w+1)) ---------------------------
  const int njb = (w >= 2) ? 2 : 1;
  bf16x8 vfr[4][2];
#pragma unroll
  for (int db = 0; db < 4; ++db)
#pragma unroll
    for (int jb = 0; jb < 2; ++jb)
      if (jb < njb)
        vfr[db][jb] =
            *(const bf16x8*)(lds + swzV(db * 16 + m, jb * 32 + g * 8));

  // ---- mm1: S^T tiles for cb = w, rb <= w ---------------------------------
  f32x4 st[4];
#pragma unroll
  for (int rb = 0; rb < 4; ++rb) {
    if (rb <= w) {
      f32x4 acc = {0.f, 0.f, 0.f, 0.f};
      acc = __builtin_amdgcn_mfma_f32_16x16x32_bf16(kf[rb][0], qf[0], acc, 0, 0, 0);
      acc = __builtin_amdgcn_mfma_f32_16x16x32_bf16(kf[rb][1], qf[1], acc, 0, 0, 0);
      st[rb] = acc;
    }
  }

  // ---- gating, C write (own 16 rows), stabilized normalizer ---------------
  char* cw = lds + 8192 + w * 2048;
  const int i = w * 16 + m;
  const float ebv = eb_sh[i];
  float rs = 0.f;
  const int rbfill = w | 1;  // zero-fill up to the jb ranges mm2 reads
#pragma unroll
  for (int rb = 0; rb < 4; ++rb) {
    if (rb <= rbfill) {
      unsigned long long wp = 0ull;
      if (rb <= w) {
        const float4 ea4 = *(const float4*)&ea_sh[rb * 16 + g * 4];
        const float eav[4] = {ea4.x, ea4.y, ea4.z, ea4.w};
#pragma unroll
        for (int e = 0; e < 4; ++e) {
          const int j = rb * 16 + g * 4 + e;
          const float val = (j <= i) ? st[rb][e] * eav[e] * ebv : 0.f;
          rs += val;
          wp |= (unsigned long long)bfbits(val) << (16 * e);
        }
      }
      *(unsigned long long*)(cw + swzC(m, rb * 16 + g * 4)) = wp;
    }
  }
  rs += __shfl_xor(rs, 16, 64);
  rs += __shfl_xor(rs, 32, 64);
  const float invv = 1.f / (fmaxf(fabsf(rs), em_sh[i]) + 1e-6f);

  // ---- mm2: H^T block for i in [16w,16w+16) -------------------------------
  const bf16x8 c0 = *(const bf16x8*)(cw + swzC(m, g * 8));
  f32x4 acc[4];
#pragma unroll
  for (int db = 0; db < 4; ++db) {
    f32x4 z = {0.f, 0.f, 0.f, 0.f};
    acc[db] = __builtin_amdgcn_mfma_f32_16x16x32_bf16(vfr[db][0], c0, z, 0, 0, 0);
  }
  if (w >= 2) {
    const bf16x8 c1 = *(const bf16x8*)(cw + swzC(m, 32 + g * 8));
#pragma unroll
    for (int db = 0; db < 4; ++db)
      acc[db] = __builtin_amdgcn_mfma_f32_16x16x32_bf16(vfr[db][1], c1, acc[db], 0, 0, 0);
  }

  // ---- normalize + store (float4, coalesced) ------------------------------
  float* op = out + cbase + i * 64 + g * 4;
#pragma unroll
  for (int db = 0; db < 4; ++db) {
    const f32x4 hv = acc[db];
    *(float4*)(op + db * 16) =
        make_float4(hv[0] * invv, hv[1] * invv, hv[2] * invv, hv[3] * invv);
  }
}

}  // namespace

extern "C" void kernel_launch(void* const* d_in, const int* in_sizes, int n_in,
                              void* d_out, int out_size, void* d_ws,
                              size_t ws_size, hipStream_t stream) {
  const float* q = (const float*)d_in[0];
  const float* k = (const float*)d_in[1];
  const float* v = (const float*)d_in[2];
  const float* ig = (const float*)d_in[3];
  const float* fg = (const float*)d_in[4];
  float* out = (float*)d_out;

  const int total = in_sizes[0];         // B*NH*S*DH
  const int nchunks = total / (L * DH);  // 2048
  mlstm_mfma<<<dim3(nchunks), dim3(256), 0, stream>>>(q, k, v, ig, fg, out);
}